// Round 3
// baseline (518.422 us; speedup 1.0000x reference)
//
#include <hip/hip_runtime.h>

#define NVV 50000
#define NCC 50000
#define DD 128
#define FIN 32
#define INDIM 288
#define DEG 16

typedef unsigned short u16;
typedef unsigned int u32;
typedef __attribute__((ext_vector_type(8))) short short8;
typedef __attribute__((ext_vector_type(4))) float f32x4;
typedef __attribute__((ext_vector_type(2))) float f32x2;

constexpr int NT = 256;

__device__ __forceinline__ float b2f(u16 b) {
  union { u32 u; float f; } v; v.u = ((u32)b) << 16; return v.f;
}
__device__ __forceinline__ u16 f2b(float f) {
  union { float f; u32 u; } v; v.f = f;
  u32 u = v.u + 0x7FFFu + ((v.u >> 16) & 1u);
  return (u16)(u >> 16);
}
__device__ __forceinline__ float bits2f(u32 u) {
  union { u32 u; float f; } v; v.u = u; return v.f;
}

// ---------------- fp32 -> bf16 convert (n multiple of 4) ----------------
__global__ __launch_bounds__(NT) void convert_kernel(
    const float* __restrict__ src, u16* __restrict__ dst, int n)
{
  int i = (blockIdx.x * NT + threadIdx.x) * 4;
  if (i < n) {
    float4 v = *(const float4*)(src + i);
    u32 lo = (u32)f2b(v.x) | ((u32)f2b(v.y) << 16);
    u32 hi = (u32)f2b(v.z) | ((u32)f2b(v.w) << 16);
    u32* d = (u32*)(dst + i);
    d[0] = lo; d[1] = hi;
  }
}

// -------- W [128][288] fp32 -> bf16 in MFMA B-fragment order --------
// frag t = kt*512 + nt*64 + lane holds W[nt*16 + (lane&15)][kt*32 + (lane>>4)*8 .. +7]
__global__ __launch_bounds__(NT) void swizzle_W(
    const float* __restrict__ W, u16* __restrict__ out)
{
  int t = blockIdx.x * NT + threadIdx.x;
  if (t >= 9 * 8 * 64) return;
  int lane = t & 63, nt = (t >> 6) & 7, kt = t >> 9;
  int li = lane & 15, quad = lane >> 4;
  const float* src = W + (size_t)(nt * 16 + li) * INDIM + kt * 32 + quad * 8;
  u32 o[4];
#pragma unroll
  for (int p = 0; p < 4; ++p)
    o[p] = (u32)f2b(src[2 * p]) | ((u32)f2b(src[2 * p + 1]) << 16);
  *(int4*)(out + (size_t)t * 8) = *(int4*)o;
}

// ---------------- init: out[r][d] = bf16(b[d] + sum_k x[r][k] * W[d][k]), K=32 ----------------
__global__ __launch_bounds__(NT) void init_kernel(
    const float* __restrict__ x, const float* __restrict__ W,
    const float* __restrict__ bias, u16* __restrict__ out, int nrows)
{
  __shared__ float in_t[32][FIN + 4];
  __shared__ float W_t[DD][FIN + 4];
  const int t = threadIdx.x;
  const int row0 = blockIdx.x * 32;
  const int nvalid = min(32, nrows - row0);

  for (int e = t; e < nvalid * FIN; e += NT)
    in_t[e >> 5][e & 31] = x[(size_t)row0 * FIN + e];
  for (int e = t; e < DD * FIN; e += NT)
    W_t[e >> 5][e & 31] = W[e];
  __syncthreads();

  const int c = t & 31, rg = t >> 5, d0 = c * 4;
  float acc[4][4];
#pragma unroll
  for (int j = 0; j < 4; ++j)
#pragma unroll
    for (int i = 0; i < 4; ++i) acc[j][i] = 0.f;

#pragma unroll
  for (int k4 = 0; k4 < FIN; k4 += 4) {
    float4 wv[4], iv[4];
#pragma unroll
    for (int i = 0; i < 4; ++i) wv[i] = *(const float4*)&W_t[d0 + i][k4];
#pragma unroll
    for (int j = 0; j < 4; ++j) iv[j] = *(const float4*)&in_t[rg * 4 + j][k4];
#pragma unroll
    for (int j = 0; j < 4; ++j)
#pragma unroll
      for (int i = 0; i < 4; ++i)
        acc[j][i] += iv[j].x * wv[i].x + iv[j].y * wv[i].y +
                     iv[j].z * wv[i].z + iv[j].w * wv[i].w;
  }
  const float4 bv = *(const float4*)&bias[d0];
#pragma unroll
  for (int j = 0; j < 4; ++j) {
    int r = rg * 4 + j;
    if (r < nvalid) {
      u32 lo = (u32)f2b(acc[j][0] + bv.x) | ((u32)f2b(acc[j][1] + bv.y) << 16);
      u32 hi = (u32)f2b(acc[j][2] + bv.z) | ((u32)f2b(acc[j][3] + bv.w) << 16);
      u32* d = (u32*)(out + (size_t)(row0 + r) * DD + d0);
      d[0] = lo; d[1] = hi;
    }
  }
}

// ------------- fused layer: out = bf16([gather|self|feat] @ W^T + b) -------------
// Zero LDS. Block = 4 waves; wave = 16 rows x 128 cols, MFMA 16x16x32.
// A frag: lane(quad,li) holds A[m=li][k=quad*8..+7]; C/D: D[quad*4+i][li].
__global__ __launch_bounds__(NT) void layer_fused(
    const u16* __restrict__ gsrc, const u16* __restrict__ self,
    const u16* __restrict__ feat, const int* __restrict__ idx,
    const u16* __restrict__ Wsw, const float* __restrict__ bias,
    u16* __restrict__ out, int nrows)
{
  const int t = threadIdx.x;
  const int wave = t >> 6, l = t & 63;
  const int quad = l >> 4, li = l & 15;
  const int r0w = blockIdx.x * 64 + wave * 16;

  // lane l holds idx[r0w + (l>>2)][(l&3)*4 .. +3]
  int4 iv;
  {
    int rload = r0w + (l >> 2);
    if (rload >= nrows) rload = nrows - 1;
    iv = *(const int4*)(idx + (size_t)rload * DEG + (l & 3) * 4);
  }
  // byte offsets of row m=li's 16 neighbor rows
  int off[DEG];
#pragma unroll
  for (int j = 0; j < DEG; ++j) {
    int comp = ((j & 3) == 0) ? iv.x : ((j & 3) == 1) ? iv.y : ((j & 3) == 2) ? iv.z : iv.w;
    off[j] = __shfl(comp, (li << 2) + (j >> 2)) << 8;  // * 256 bytes per row
  }

  int rowm = r0w + li;
  if (rowm >= nrows) rowm = nrows - 1;

  f32x4 acc[8];
#pragma unroll
  for (int nt = 0; nt < 8; ++nt) acc[nt] = (f32x4){0.f, 0.f, 0.f, 0.f};

  // ---- feat tile (kt = 8) ----
  {
    short8 a = *(const short8*)(feat + (size_t)rowm * FIN + quad * 8);
#pragma unroll
    for (int nt = 0; nt < 8; ++nt) {
      short8 b = *(const short8*)(Wsw + (size_t)((8 * 8 + nt) * 64 + l) * 8);
      acc[nt] = __builtin_amdgcn_mfma_f32_16x16x32_bf16(a, b, acc[nt], 0, 0, 0);
    }
  }
  // ---- self tiles (kt = 4..7) ----
#pragma unroll
  for (int k2 = 0; k2 < 4; ++k2) {
    short8 a = *(const short8*)(self + (size_t)rowm * DD + k2 * 32 + quad * 8);
#pragma unroll
    for (int nt = 0; nt < 8; ++nt) {
      short8 b = *(const short8*)(Wsw + (size_t)(((4 + k2) * 8 + nt) * 64 + l) * 8);
      acc[nt] = __builtin_amdgcn_mfma_f32_16x16x32_bf16(a, b, acc[nt], 0, 0, 0);
    }
  }
  // ---- gathered-aggregate tiles (kt = 0..3) ----
#pragma unroll
  for (int k2 = 0; k2 < 4; ++k2) {
    f32x2 s[4];
#pragma unroll
    for (int p = 0; p < 4; ++p) s[p] = (f32x2){0.f, 0.f};
#pragma unroll
    for (int j = 0; j < DEG; ++j) {
      int4 v = *(const int4*)((const char*)gsrc + (size_t)(u32)off[j] + k2 * 64 + quad * 16);
      const u32* w = (const u32*)&v;
#pragma unroll
      for (int p = 0; p < 4; ++p) {
        f32x2 e = (f32x2){bits2f(w[p] << 16), bits2f(w[p] & 0xFFFF0000u)};
        s[p] += e;
      }
    }
    u32 a_bits[4];
#pragma unroll
    for (int p = 0; p < 4; ++p)
      a_bits[p] = (u32)f2b(s[p].x) | ((u32)f2b(s[p].y) << 16);
    short8 a = *(short8*)a_bits;
#pragma unroll
    for (int nt = 0; nt < 8; ++nt) {
      short8 b = *(const short8*)(Wsw + (size_t)((k2 * 8 + nt) * 64 + l) * 8);
      acc[nt] = __builtin_amdgcn_mfma_f32_16x16x32_bf16(a, b, acc[nt], 0, 0, 0);
    }
  }

  // ---- epilogue ----
  const int rbase = r0w + quad * 4;
#pragma unroll
  for (int nt = 0; nt < 8; ++nt) {
    const int col = nt * 16 + li;
    const float bv = bias[col];
#pragma unroll
    for (int i = 0; i < 4; ++i) {
      const int row = rbase + i;
      if (row < nrows) out[(size_t)row * DD + col] = f2b(acc[nt][i] + bv);
    }
  }
}

// ---------------- g = sum_r lv[r][:] ----------------
__global__ void zero_g(float* g) { g[threadIdx.x] = 0.f; }

__global__ __launch_bounds__(NT) void reduce_kernel(
    const u16* __restrict__ lv, float* __restrict__ g, int nrows)
{
  __shared__ float sh[NT];
  const int t = threadIdx.x;
  const int d = t & 127, rh = t >> 7;
  float p = 0.f;
  for (int r = blockIdx.x * 2 + rh; r < nrows; r += gridDim.x * 2)
    p += b2f(lv[(size_t)r * DD + d]);
  sh[t] = p;
  __syncthreads();
  if (t < 128) atomicAdd(&g[d], sh[t] + sh[t + 128]);
}

// ------------- Q[r] = b_q + dot(Wq[0:128], g) + dot(Wq[128:256], lv[r]) -------------
__global__ __launch_bounds__(NT) void final_kernel(
    const u16* __restrict__ lv, const float* __restrict__ g,
    const float* __restrict__ Wq, const float* __restrict__ bq,
    float* __restrict__ out, int nrows)
{
  __shared__ float wsum[4];
  __shared__ float qg_s;
  const int t = threadIdx.x;
  float q = (t < DD) ? Wq[t] * g[t] : 0.f;
#pragma unroll
  for (int off = 32; off; off >>= 1) q += __shfl_down(q, off);
  if ((t & 63) == 0) wsum[t >> 6] = q;
  __syncthreads();
  if (t == 0) qg_s = wsum[0] + wsum[1] + bq[0];
  __syncthreads();

  const int d = t & 127, rh = t >> 7;
  const int r = blockIdx.x * 2 + rh;
  float p = 0.f;
  if (r < nrows) p = Wq[DD + d] * b2f(lv[(size_t)r * DD + d]);
#pragma unroll
  for (int off = 32; off; off >>= 1) p += __shfl_down(p, off);
  if ((t & 63) == 0) wsum[t >> 6] = p;
  __syncthreads();
  if (t == 0 && r < nrows) out[r] = qg_s + wsum[0] + wsum[1];
  if (t == 128 && r < nrows) out[r] = qg_s + wsum[2] + wsum[3];
}

extern "C" void kernel_launch(void* const* d_in, const int* in_sizes, int n_in,
                              void* d_out, int out_size, void* d_ws, size_t ws_size,
                              hipStream_t stream) {
  const float* x    = (const float*)d_in[0];
  const int*   vci  = (const int*)d_in[1];   // var_constr_index [NV][16] -> gathers from lc
  const int*   cvi  = (const int*)d_in[2];   // constr_var_index [NC][16] -> gathers from lv
  const float* W_iv = (const float*)d_in[3];
  const float* b_iv = (const float*)d_in[4];
  const float* W_ic = (const float*)d_in[5];
  const float* b_ic = (const float*)d_in[6];
  const float* W_v  = (const float*)d_in[7];
  const float* b_v  = (const float*)d_in[8];
  const float* W_c  = (const float*)d_in[9];
  const float* b_c  = (const float*)d_in[10];
  const float* W_q  = (const float*)d_in[11];
  const float* b_q  = (const float*)d_in[12];
  float* out = (float*)d_out;

  // workspace: g (fp32) | xb | Wv_sw | Wc_sw | lv0 | lc0 | lv1 | lc1   (bf16, 16B aligned)
  float* g = (float*)d_ws;
  u16* base = (u16*)((char*)d_ws + 512);
  const size_t nodef = (size_t)NVV * DD;
  u16* xb   = base;                              // 100000*32
  u16* Wvsw = xb + (size_t)(NVV + NCC) * FIN;    // 36864
  u16* Wcsw = Wvsw + (size_t)DD * INDIM;
  u16* lv0  = Wcsw + (size_t)DD * INDIM;
  u16* lc0  = lv0 + nodef;
  u16* lv1  = lc0 + nodef;
  u16* lc1  = lv1 + nodef;
  u16* xvb  = xb;
  u16* xcb  = xb + (size_t)NVV * FIN;

  dim3 blk(NT);

  convert_kernel<<<((NVV + NCC) * FIN / 4 + NT - 1) / NT, blk, 0, stream>>>(x, xb, (NVV + NCC) * FIN);
  swizzle_W<<<(9 * 8 * 64 + NT - 1) / NT, blk, 0, stream>>>(W_v, Wvsw);
  swizzle_W<<<(9 * 8 * 64 + NT - 1) / NT, blk, 0, stream>>>(W_c, Wcsw);

  const int grid_init = (NVV + 31) / 32;
  init_kernel<<<grid_init, blk, 0, stream>>>(x, W_iv, b_iv, lv0, NVV);
  init_kernel<<<grid_init, blk, 0, stream>>>(x + (size_t)NVV * FIN, W_ic, b_ic, lc0, NCC);

  const int grid_layer = (NVV + 63) / 64;   // 782

  u16* lv_cur = lv0; u16* lc_cur = lc0;
  u16* lv_nxt = lv1; u16* lc_nxt = lc1;
  for (int lyr = 0; lyr < 3; ++lyr) {
    // lc_new = [gather(lv_old, cvi) | lc_old | con_feat] @ W_c^T + b_c
    layer_fused<<<grid_layer, blk, 0, stream>>>(lv_cur, lc_cur, xcb, cvi, Wcsw, b_c, lc_nxt, NCC);
    // lv_new = [gather(lc_old, vci) | lv_old | var_feat] @ W_v^T + b_v
    layer_fused<<<grid_layer, blk, 0, stream>>>(lc_cur, lv_cur, xvb, vci, Wvsw, b_v, lv_nxt, NVV);
    u16* tv = lv_cur; lv_cur = lv_nxt; lv_nxt = tv;
    u16* tc = lc_cur; lc_cur = lc_nxt; lc_nxt = tc;
  }

  zero_g<<<1, 128, 0, stream>>>(g);
  reduce_kernel<<<256, blk, 0, stream>>>(lv_cur, g, NVV);
  final_kernel<<<NVV / 2, blk, 0, stream>>>(lv_cur, g, W_q, b_q, out, NVV);
}

// Round 4
// 421.413 us; speedup vs baseline: 1.2302x; 1.2302x over previous
//
#include <hip/hip_runtime.h>

#define NVV 50000
#define NCC 50000
#define DD 128
#define FIN 32
#define INDIM 288
#define DEG 16

typedef unsigned short u16;
typedef unsigned int u32;
typedef __attribute__((ext_vector_type(8))) short short8;
typedef __attribute__((ext_vector_type(4))) float f32x4;
typedef __attribute__((ext_vector_type(2))) float f32x2;

constexpr int NT = 256;
constexpr int GRID_HALF = 782;   // ceil(50000/64)

__device__ __forceinline__ float b2f(u16 b) {
  union { u32 u; float f; } v; v.u = ((u32)b) << 16; return v.f;
}
__device__ __forceinline__ u16 f2b(float f) {
  union { float f; u32 u; } v; v.f = f;
  u32 u = v.u + 0x7FFFu + ((v.u >> 16) & 1u);
  return (u16)(u >> 16);
}
__device__ __forceinline__ float bits2f(u32 u) {
  union { u32 u; float f; } v; v.u = u; return v.f;
}
__device__ __forceinline__ u32 pack2(float a, float b) {
  return (u32)f2b(a) | ((u32)f2b(b) << 16);
}

// -------- all weights fp32 -> bf16 MFMA B-fragment order, one kernel --------
// frag f = kt*512 + nt*64 + lane holds W[nt*16+(lane&15)][kt*32+(lane>>4)*8 .. +7]
__global__ __launch_bounds__(NT) void swizzle_all(
    const float* __restrict__ Wv, const float* __restrict__ Wc,
    const float* __restrict__ Wiv, const float* __restrict__ Wic,
    u16* __restrict__ Wvsw, u16* __restrict__ Wcsw,
    u16* __restrict__ Wivsw, u16* __restrict__ Wicsw)
{
  int t = blockIdx.x * NT + threadIdx.x;
  if (t >= 10240) return;
  const float* W; u16* out; int f; int indim;
  if (t < 4608)       { W = Wv;  out = Wvsw;  f = t;        indim = INDIM; }
  else if (t < 9216)  { W = Wc;  out = Wcsw;  f = t - 4608; indim = INDIM; }
  else if (t < 9728)  { W = Wiv; out = Wivsw; f = t - 9216; indim = FIN; }
  else                { W = Wic; out = Wicsw; f = t - 9728; indim = FIN; }
  int lane = f & 63, nt = (f >> 6) & 7, kt = f >> 9;
  int li = lane & 15, quad = lane >> 4;
  const float* src = W + (size_t)(nt * 16 + li) * indim + kt * 32 + quad * 8;
  float4 a = *(const float4*)src, b = *(const float4*)(src + 4);
  u32 o[4] = { pack2(a.x, a.y), pack2(a.z, a.w), pack2(b.x, b.y), pack2(b.z, b.w) };
  *(int4*)(out + (size_t)f * 8) = *(int4*)o;
}

// -------- init (MFMA, fused x->bf16 feat emit): out = bf16(x @ W^T + b) --------
// grid 1564: blocks [0,782) = V side, [782,1564) = C side.
__global__ __launch_bounds__(NT) void init_fused(
    const float* __restrict__ x,
    const u16* __restrict__ Wivsw, const u16* __restrict__ Wicsw,
    const float* __restrict__ b_iv, const float* __restrict__ b_ic,
    u16* __restrict__ lv0, u16* __restrict__ lc0,
    u16* __restrict__ xvb, u16* __restrict__ xcb)
{
  const int bid = blockIdx.x;
  const bool isC = bid >= GRID_HALF;
  const int lb = isC ? bid - GRID_HALF : bid;
  const float* xs = x + (isC ? (size_t)NVV * FIN : 0);
  const u16* Wsw = isC ? Wicsw : Wivsw;
  const float* bias = isC ? b_ic : b_iv;
  u16* out  = isC ? lc0 : lv0;
  u16* feat = isC ? xcb : xvb;
  const int nrows = isC ? NCC : NVV;

  const int t = threadIdx.x;
  const int r0 = lb * 64;

  // feat convert+store: thread t handles row r0+(t>>2), cols (t&3)*8..+7
  {
    const int row = r0 + (t >> 2);
    if (row < nrows) {
      const float* src = xs + (size_t)row * FIN + (t & 3) * 8;
      float4 a = *(const float4*)src, b = *(const float4*)(src + 4);
      u32 o[4] = { pack2(a.x, a.y), pack2(a.z, a.w), pack2(b.x, b.y), pack2(b.z, b.w) };
      *(int4*)(feat + (size_t)row * FIN + (t & 3) * 8) = *(int4*)o;
    }
  }

  // MFMA: wave = 16 rows x 128 cols, single K=32 tile
  const int wave = t >> 6, l = t & 63;
  const int quad = l >> 4, li = l & 15;
  const int r0w = r0 + wave * 16;
  int rowm = r0w + li;
  if (rowm >= nrows) rowm = nrows - 1;

  short8 afrag;
  {
    const float* src = xs + (size_t)rowm * FIN + quad * 8;
    float4 a = *(const float4*)src, b = *(const float4*)(src + 4);
    u32 o[4] = { pack2(a.x, a.y), pack2(a.z, a.w), pack2(b.x, b.y), pack2(b.z, b.w) };
    afrag = *(short8*)o;
  }

  f32x4 acc[8];
#pragma unroll
  for (int nt = 0; nt < 8; ++nt) acc[nt] = (f32x4){0.f, 0.f, 0.f, 0.f};
#pragma unroll
  for (int nt = 0; nt < 8; ++nt) {
    short8 b = *(const short8*)(Wsw + (size_t)(nt * 64 + l) * 8);
    acc[nt] = __builtin_amdgcn_mfma_f32_16x16x32_bf16(afrag, b, acc[nt], 0, 0, 0);
  }

  const int rbase = r0w + quad * 4;
#pragma unroll
  for (int nt = 0; nt < 8; ++nt) {
    const int col = nt * 16 + li;
    const float bv = bias[col];
#pragma unroll
    for (int i = 0; i < 4; ++i) {
      const int row = rbase + i;
      if (row < nrows) out[(size_t)row * DD + col] = f2b(acc[nt][i] + bv);
    }
  }
}

// ------------- fused layer body: out = bf16([gather|self|feat] @ W^T + b) -------------
__device__ __forceinline__ void layer_body(
    const u16* __restrict__ gsrc, const u16* __restrict__ self,
    const u16* __restrict__ feat, const int* __restrict__ idx,
    const u16* __restrict__ Wsw, const float* __restrict__ bias,
    u16* __restrict__ out, int nrows, int bid, int t)
{
  const int wave = t >> 6, l = t & 63;
  const int quad = l >> 4, li = l & 15;
  const int r0w = bid * 64 + wave * 16;

  // lane l holds idx[r0w + (l>>2)][(l&3)*4 .. +3]
  int4 iv;
  {
    int rload = r0w + (l >> 2);
    if (rload >= nrows) rload = nrows - 1;
    iv = *(const int4*)(idx + (size_t)rload * DEG + (l & 3) * 4);
  }
  int off[DEG];
#pragma unroll
  for (int j = 0; j < DEG; ++j) {
    int comp = ((j & 3) == 0) ? iv.x : ((j & 3) == 1) ? iv.y : ((j & 3) == 2) ? iv.z : iv.w;
    off[j] = __shfl(comp, (li << 2) + (j >> 2)) << 8;  // * 256 B per bf16 row
  }

  int rowm = r0w + li;
  if (rowm >= nrows) rowm = nrows - 1;

  f32x4 acc[8];
#pragma unroll
  for (int nt = 0; nt < 8; ++nt) acc[nt] = (f32x4){0.f, 0.f, 0.f, 0.f};

  // ---- feat tile (kt = 8) ----
  {
    short8 a = *(const short8*)(feat + (size_t)rowm * FIN + quad * 8);
#pragma unroll
    for (int nt = 0; nt < 8; ++nt) {
      short8 b = *(const short8*)(Wsw + (size_t)((8 * 8 + nt) * 64 + l) * 8);
      acc[nt] = __builtin_amdgcn_mfma_f32_16x16x32_bf16(a, b, acc[nt], 0, 0, 0);
    }
  }
  // ---- self tiles (kt = 4..7) ----
#pragma unroll
  for (int k2 = 0; k2 < 4; ++k2) {
    short8 a = *(const short8*)(self + (size_t)rowm * DD + k2 * 32 + quad * 8);
#pragma unroll
    for (int nt = 0; nt < 8; ++nt) {
      short8 b = *(const short8*)(Wsw + (size_t)(((4 + k2) * 8 + nt) * 64 + l) * 8);
      acc[nt] = __builtin_amdgcn_mfma_f32_16x16x32_bf16(a, b, acc[nt], 0, 0, 0);
    }
  }
  // ---- gathered-aggregate tiles (kt = 0..3) ----
#pragma unroll
  for (int k2 = 0; k2 < 4; ++k2) {
    f32x2 s[4];
#pragma unroll
    for (int p = 0; p < 4; ++p) s[p] = (f32x2){0.f, 0.f};
#pragma unroll
    for (int j = 0; j < DEG; ++j) {
      int4 v = *(const int4*)((const char*)gsrc + (size_t)(u32)off[j] + k2 * 64 + quad * 16);
      const u32* w = (const u32*)&v;
#pragma unroll
      for (int p = 0; p < 4; ++p) {
        f32x2 e = (f32x2){bits2f(w[p] << 16), bits2f(w[p] & 0xFFFF0000u)};
        s[p] += e;
      }
    }
    u32 a_bits[4];
#pragma unroll
    for (int p = 0; p < 4; ++p)
      a_bits[p] = (u32)f2b(s[p].x) | ((u32)f2b(s[p].y) << 16);
    short8 a = *(short8*)a_bits;
#pragma unroll
    for (int nt = 0; nt < 8; ++nt) {
      short8 b = *(const short8*)(Wsw + (size_t)((k2 * 8 + nt) * 64 + l) * 8);
      acc[nt] = __builtin_amdgcn_mfma_f32_16x16x32_bf16(a, b, acc[nt], 0, 0, 0);
    }
  }

  const int rbase = r0w + quad * 4;
#pragma unroll
  for (int nt = 0; nt < 8; ++nt) {
    const int col = nt * 16 + li;
    const float bv = bias[col];
#pragma unroll
    for (int i = 0; i < 4; ++i) {
      const int row = rbase + i;
      if (row < nrows) out[(size_t)row * DD + col] = f2b(acc[nt][i] + bv);
    }
  }
}

// merged: blocks [0,c_blocks) do the C update, the rest do the V update.
__global__ __launch_bounds__(NT) void layer_merged(
    const u16* gsrcC, const u16* selfC, const u16* featC, const int* idxC,
    const u16* WswC, const float* biasC, u16* outC, int nrowsC,
    const u16* gsrcV, const u16* selfV, const u16* featV, const int* idxV,
    const u16* WswV, const float* biasV, u16* outV, int nrowsV,
    int c_blocks)
{
  const int bid = blockIdx.x;
  const int t = threadIdx.x;
  if (bid < c_blocks)
    layer_body(gsrcC, selfC, featC, idxC, WswC, biasC, outC, nrowsC, bid, t);
  else
    layer_body(gsrcV, selfV, featV, idxV, WswV, biasV, outV, nrowsV, bid - c_blocks, t);
}

// ---------------- g = sum_r lv[r][:] ----------------
__global__ void zero_g(float* g) { g[threadIdx.x] = 0.f; }

__global__ __launch_bounds__(NT) void reduce_kernel(
    const u16* __restrict__ lv, float* __restrict__ g, int nrows)
{
  __shared__ float sh[NT];
  const int t = threadIdx.x;
  const int d = t & 127, rh = t >> 7;
  float p = 0.f;
  for (int r = blockIdx.x * 2 + rh; r < nrows; r += gridDim.x * 2)
    p += b2f(lv[(size_t)r * DD + d]);
  sh[t] = p;
  __syncthreads();
  if (t < 128) atomicAdd(&g[d], sh[t] + sh[t + 128]);
}

// ------------- Q[r] = b_q + dot(Wq[0:128], g) + dot(Wq[128:256], lv[r]) -------------
// grid 782: wave handles 16 rows, lane covers 2 cols (coalesced 256B row reads)
__global__ __launch_bounds__(NT) void final_kernel(
    const u16* __restrict__ lv, const float* __restrict__ g,
    const float* __restrict__ Wq, const float* __restrict__ bq,
    float* __restrict__ out)
{
  const int t = threadIdx.x, wave = t >> 6, l = t & 63;
  const float2 wg = *(const float2*)(Wq + 2 * l);
  const float2 wl = *(const float2*)(Wq + DD + 2 * l);
  const float2 gv = *(const float2*)(g + 2 * l);
  float q = wg.x * gv.x + wg.y * gv.y;
#pragma unroll
  for (int off = 32; off; off >>= 1) q += __shfl_down(q, off);
  const float qg = __shfl(q, 0) + bq[0];

  const int r0w = blockIdx.x * 64 + wave * 16;
#pragma unroll
  for (int i = 0; i < 16; ++i) {
    const int r = r0w + i;
    if (r >= NVV) break;
    u32 v = *(const u32*)(lv + (size_t)r * DD + 2 * l);
    float p = wl.x * b2f((u16)(v & 0xFFFF)) + wl.y * b2f((u16)(v >> 16));
#pragma unroll
    for (int off = 32; off; off >>= 1) p += __shfl_down(p, off);
    if (l == 0) out[r] = qg + p;
  }
}

extern "C" void kernel_launch(void* const* d_in, const int* in_sizes, int n_in,
                              void* d_out, int out_size, void* d_ws, size_t ws_size,
                              hipStream_t stream) {
  const float* x    = (const float*)d_in[0];
  const int*   vci  = (const int*)d_in[1];   // var_constr_index [NV][16] -> gathers from lc
  const int*   cvi  = (const int*)d_in[2];   // constr_var_index [NC][16] -> gathers from lv
  const float* W_iv = (const float*)d_in[3];
  const float* b_iv = (const float*)d_in[4];
  const float* W_ic = (const float*)d_in[5];
  const float* b_ic = (const float*)d_in[6];
  const float* W_v  = (const float*)d_in[7];
  const float* b_v  = (const float*)d_in[8];
  const float* W_c  = (const float*)d_in[9];
  const float* b_c  = (const float*)d_in[10];
  const float* W_q  = (const float*)d_in[11];
  const float* b_q  = (const float*)d_in[12];
  float* out = (float*)d_out;

  // workspace: g | xb | Wvsw | Wcsw | Wivsw | Wicsw | lv0 | lc0 | lv1 | lc1
  float* g = (float*)d_ws;
  u16* base = (u16*)((char*)d_ws + 512);
  const size_t nodef = (size_t)NVV * DD;
  u16* xb    = base;                               // 100000*32
  u16* Wvsw  = xb + (size_t)(NVV + NCC) * FIN;
  u16* Wcsw  = Wvsw + (size_t)DD * INDIM;
  u16* Wivsw = Wcsw + (size_t)DD * INDIM;
  u16* Wicsw = Wivsw + (size_t)DD * FIN;
  u16* lv0   = Wicsw + (size_t)DD * FIN;
  u16* lc0   = lv0 + nodef;
  u16* lv1   = lc0 + nodef;
  u16* lc1   = lv1 + nodef;
  u16* xvb   = xb;
  u16* xcb   = xb + (size_t)NVV * FIN;

  dim3 blk(NT);

  swizzle_all<<<40, blk, 0, stream>>>(W_v, W_c, W_iv, W_ic, Wvsw, Wcsw, Wivsw, Wicsw);
  init_fused<<<2 * GRID_HALF, blk, 0, stream>>>(x, Wivsw, Wicsw, b_iv, b_ic,
                                                lv0, lc0, xvb, xcb);

  // iteration 0: lc1 = f(gather lv0, lc0); lv1 = f(gather lc0, lv0)
  layer_merged<<<2 * GRID_HALF, blk, 0, stream>>>(
      lv0, lc0, xcb, cvi, Wcsw, b_c, lc1, NCC,
      lc0, lv0, xvb, vci, Wvsw, b_v, lv1, NVV, GRID_HALF);
  // iteration 1: lc0 = f(gather lv1, lc1); lv0 = f(gather lc1, lv1)
  layer_merged<<<2 * GRID_HALF, blk, 0, stream>>>(
      lv1, lc1, xcb, cvi, Wcsw, b_c, lc0, NCC,
      lc1, lv1, xvb, vci, Wvsw, b_v, lv0, NVV, GRID_HALF);
  // iteration 2: only lv needed (last lc update is dead in the reference)
  layer_merged<<<GRID_HALF, blk, 0, stream>>>(
      lv0, lc0, xcb, cvi, Wcsw, b_c, lc1, NCC,   // unused side
      lc0, lv0, xvb, vci, Wvsw, b_v, lv1, NVV, 0);

  zero_g<<<1, 128, 0, stream>>>(g);
  reduce_kernel<<<256, blk, 0, stream>>>(lv1, g, NVV);
  final_kernel<<<GRID_HALF, blk, 0, stream>>>(lv1, g, W_q, b_q, out);
}

// Round 5
// 378.230 us; speedup vs baseline: 1.3707x; 1.1142x over previous
//
#include <hip/hip_runtime.h>

#define NVV 50000
#define NCC 50000
#define DD 128
#define FIN 32
#define INDIM 288
#define DEG 16

typedef unsigned short u16;
typedef unsigned int u32;
typedef __attribute__((ext_vector_type(8))) short short8;
typedef __attribute__((ext_vector_type(4))) float f32x4;
typedef __attribute__((ext_vector_type(2))) float f32x2;

constexpr int NT = 256;
constexpr int GRID_HALF = 782;   // ceil(50000/64)

__device__ __forceinline__ float b2f(u16 b) {
  union { u32 u; float f; } v; v.u = ((u32)b) << 16; return v.f;
}
__device__ __forceinline__ u16 f2b(float f) {
  union { float f; u32 u; } v; v.f = f;
  u32 u = v.u + 0x7FFFu + ((v.u >> 16) & 1u);
  return (u16)(u >> 16);
}
__device__ __forceinline__ float bits2f(u32 u) {
  union { u32 u; float f; } v; v.u = u; return v.f;
}
__device__ __forceinline__ u32 pack2(float a, float b) {
  return (u32)f2b(a) | ((u32)f2b(b) << 16);
}

// -------- all weights fp32 -> bf16 MFMA B-fragment order, one kernel --------
// frag f = kt*512 + nt*64 + lane holds W[nt*16+(lane&15)][kt*32+(lane>>4)*8 .. +7]
__global__ __launch_bounds__(NT) void swizzle_all(
    const float* __restrict__ Wv, const float* __restrict__ Wc,
    const float* __restrict__ Wiv, const float* __restrict__ Wic,
    u16* __restrict__ Wvsw, u16* __restrict__ Wcsw,
    u16* __restrict__ Wivsw, u16* __restrict__ Wicsw)
{
  int t = blockIdx.x * NT + threadIdx.x;
  if (t >= 10240) return;
  const float* W; u16* out; int f; int indim;
  if (t < 4608)       { W = Wv;  out = Wvsw;  f = t;        indim = INDIM; }
  else if (t < 9216)  { W = Wc;  out = Wcsw;  f = t - 4608; indim = INDIM; }
  else if (t < 9728)  { W = Wiv; out = Wivsw; f = t - 9216; indim = FIN; }
  else                { W = Wic; out = Wicsw; f = t - 9728; indim = FIN; }
  int lane = f & 63, nt = (f >> 6) & 7, kt = f >> 9;
  int li = lane & 15, quad = lane >> 4;
  const float* src = W + (size_t)(nt * 16 + li) * indim + kt * 32 + quad * 8;
  float4 a = *(const float4*)src, b = *(const float4*)(src + 4);
  u32 o[4] = { pack2(a.x, a.y), pack2(a.z, a.w), pack2(b.x, b.y), pack2(b.z, b.w) };
  *(int4*)(out + (size_t)f * 8) = *(int4*)o;
}

// -------- init (MFMA, fused x->bf16 feat emit): out = bf16(x @ W^T + b) --------
__global__ __launch_bounds__(NT) void init_fused(
    const float* __restrict__ x,
    const u16* __restrict__ Wivsw, const u16* __restrict__ Wicsw,
    const float* __restrict__ b_iv, const float* __restrict__ b_ic,
    u16* __restrict__ lv0, u16* __restrict__ lc0,
    u16* __restrict__ xvb, u16* __restrict__ xcb)
{
  const int bid = blockIdx.x;
  const bool isC = bid >= GRID_HALF;
  const int lb = isC ? bid - GRID_HALF : bid;
  const float* xs = x + (isC ? (size_t)NVV * FIN : 0);
  const u16* Wsw = isC ? Wicsw : Wivsw;
  const float* bias = isC ? b_ic : b_iv;
  u16* out  = isC ? lc0 : lv0;
  u16* feat = isC ? xcb : xvb;
  const int nrows = isC ? NCC : NVV;

  const int t = threadIdx.x;
  const int r0 = lb * 64;

  {
    const int row = r0 + (t >> 2);
    if (row < nrows) {
      const float* src = xs + (size_t)row * FIN + (t & 3) * 8;
      float4 a = *(const float4*)src, b = *(const float4*)(src + 4);
      u32 o[4] = { pack2(a.x, a.y), pack2(a.z, a.w), pack2(b.x, b.y), pack2(b.z, b.w) };
      *(int4*)(feat + (size_t)row * FIN + (t & 3) * 8) = *(int4*)o;
    }
  }

  const int wave = t >> 6, l = t & 63;
  const int quad = l >> 4, li = l & 15;
  const int r0w = r0 + wave * 16;
  int rowm = r0w + li;
  if (rowm >= nrows) rowm = nrows - 1;

  short8 afrag;
  {
    const float* src = xs + (size_t)rowm * FIN + quad * 8;
    float4 a = *(const float4*)src, b = *(const float4*)(src + 4);
    u32 o[4] = { pack2(a.x, a.y), pack2(a.z, a.w), pack2(b.x, b.y), pack2(b.z, b.w) };
    afrag = *(short8*)o;
  }

  f32x4 acc[8];
#pragma unroll
  for (int nt = 0; nt < 8; ++nt) acc[nt] = (f32x4){0.f, 0.f, 0.f, 0.f};
#pragma unroll
  for (int nt = 0; nt < 8; ++nt) {
    short8 b = *(const short8*)(Wsw + (size_t)(nt * 64 + l) * 8);
    acc[nt] = __builtin_amdgcn_mfma_f32_16x16x32_bf16(afrag, b, acc[nt], 0, 0, 0);
  }

  const int rbase = r0w + quad * 4;
#pragma unroll
  for (int nt = 0; nt < 8; ++nt) {
    const int col = nt * 16 + li;
    const float bv = bias[col];
#pragma unroll
    for (int i = 0; i < 4; ++i) {
      const int row = rbase + i;
      if (row < nrows) out[(size_t)row * DD + col] = f2b(acc[nt][i] + bv);
    }
  }
}

// ------------- fused layer body: out = bf16([gather|self|feat] @ W^T + b) -------------
// Gather restructured j-major: 32 int4 loads in flight per batch, fp32 accum for
// all 4 k-tiles at once; feat/self MFMA tiles overlap batch-0 miss latency.
__device__ __forceinline__ void layer_body(
    const u16* __restrict__ gsrc, const u16* __restrict__ self,
    const u16* __restrict__ feat, const int* __restrict__ idx,
    const u16* __restrict__ Wsw, const float* __restrict__ bias,
    u16* __restrict__ out, int nrows, int bid, int t)
{
  const int wave = t >> 6, l = t & 63;
  const int quad = l >> 4, li = l & 15;
  const int r0w = bid * 64 + wave * 16;

  // lane l holds idx[r0w + (l>>2)][(l&3)*4 .. +3]
  int4 iv;
  {
    int rload = r0w + (l >> 2);
    if (rload >= nrows) rload = nrows - 1;
    iv = *(const int4*)(idx + (size_t)rload * DEG + (l & 3) * 4);
  }
  int off[DEG];
#pragma unroll
  for (int j = 0; j < DEG; ++j) {
    int comp = ((j & 3) == 0) ? iv.x : ((j & 3) == 1) ? iv.y : ((j & 3) == 2) ? iv.z : iv.w;
    off[j] = __shfl(comp, (li << 2) + (j >> 2)) << 8;  // * 256 B per bf16 row
  }

  int rowm = r0w + li;
  if (rowm >= nrows) rowm = nrows - 1;

  f32x4 acc[8];
#pragma unroll
  for (int nt = 0; nt < 8; ++nt) acc[nt] = (f32x4){0.f, 0.f, 0.f, 0.f};

  // fp32 accumulators for all 4 gather k-tiles
  f32x2 sagg[4][4];
#pragma unroll
  for (int k2 = 0; k2 < 4; ++k2)
#pragma unroll
    for (int p = 0; p < 4; ++p) sagg[k2][p] = (f32x2){0.f, 0.f};

  const char* gp = (const char*)gsrc + quad * 16;

  // ---- batch 0: issue 32 gather loads (j = 0..7, all 4 k-tiles) ----
  int4 buf[8][4];
#pragma unroll
  for (int j = 0; j < 8; ++j) {
    const char* rp = gp + (size_t)(u32)off[j];
#pragma unroll
    for (int k2 = 0; k2 < 4; ++k2) buf[j][k2] = *(const int4*)(rp + k2 * 64);
  }

  // ---- overlap with dense tiles: feat (kt=8) + self (kt=4..7) ----
  {
    short8 a = *(const short8*)(feat + (size_t)rowm * FIN + quad * 8);
#pragma unroll
    for (int nt = 0; nt < 8; ++nt) {
      short8 b = *(const short8*)(Wsw + (size_t)((8 * 8 + nt) * 64 + l) * 8);
      acc[nt] = __builtin_amdgcn_mfma_f32_16x16x32_bf16(a, b, acc[nt], 0, 0, 0);
    }
  }
#pragma unroll
  for (int k2 = 0; k2 < 4; ++k2) {
    short8 a = *(const short8*)(self + (size_t)rowm * DD + k2 * 32 + quad * 8);
#pragma unroll
    for (int nt = 0; nt < 8; ++nt) {
      short8 b = *(const short8*)(Wsw + (size_t)(((4 + k2) * 8 + nt) * 64 + l) * 8);
      acc[nt] = __builtin_amdgcn_mfma_f32_16x16x32_bf16(a, b, acc[nt], 0, 0, 0);
    }
  }

  // ---- consume batch 0 / issue+consume batch 1 ----
#pragma unroll
  for (int jb = 0; jb < 2; ++jb) {
    if (jb) {
#pragma unroll
      for (int j = 0; j < 8; ++j) {
        const char* rp = gp + (size_t)(u32)off[8 + j];
#pragma unroll
        for (int k2 = 0; k2 < 4; ++k2) buf[j][k2] = *(const int4*)(rp + k2 * 64);
      }
    }
#pragma unroll
    for (int j = 0; j < 8; ++j)
#pragma unroll
      for (int k2 = 0; k2 < 4; ++k2) {
        const u32* w = (const u32*)&buf[j][k2];
#pragma unroll
        for (int p = 0; p < 4; ++p)
          sagg[k2][p] += (f32x2){bits2f(w[p] << 16), bits2f(w[p] & 0xFFFF0000u)};
      }
  }

  // ---- gather-tile MFMAs (kt = 0..3) ----
#pragma unroll
  for (int k2 = 0; k2 < 4; ++k2) {
    u32 a_bits[4];
#pragma unroll
    for (int p = 0; p < 4; ++p) a_bits[p] = pack2(sagg[k2][p].x, sagg[k2][p].y);
    short8 a = *(short8*)a_bits;
#pragma unroll
    for (int nt = 0; nt < 8; ++nt) {
      short8 b = *(const short8*)(Wsw + (size_t)((k2 * 8 + nt) * 64 + l) * 8);
      acc[nt] = __builtin_amdgcn_mfma_f32_16x16x32_bf16(a, b, acc[nt], 0, 0, 0);
    }
  }

  const int rbase = r0w + quad * 4;
#pragma unroll
  for (int nt = 0; nt < 8; ++nt) {
    const int col = nt * 16 + li;
    const float bv = bias[col];
#pragma unroll
    for (int i = 0; i < 4; ++i) {
      const int row = rbase + i;
      if (row < nrows) out[(size_t)row * DD + col] = f2b(acc[nt][i] + bv);
    }
  }
}

// merged: blocks [0,c_blocks) do the C update, the rest do the V update.
// launch_bounds(256,2): VGPR cap 256 so the 32-load batch stays in registers.
__global__ __launch_bounds__(NT, 2) void layer_merged(
    const u16* gsrcC, const u16* selfC, const u16* featC, const int* idxC,
    const u16* WswC, const float* biasC, u16* outC, int nrowsC,
    const u16* gsrcV, const u16* selfV, const u16* featV, const int* idxV,
    const u16* WswV, const float* biasV, u16* outV, int nrowsV,
    int c_blocks)
{
  const int bid = blockIdx.x;
  const int t = threadIdx.x;
  if (bid < c_blocks)
    layer_body(gsrcC, selfC, featC, idxC, WswC, biasC, outC, nrowsC, bid, t);
  else
    layer_body(gsrcV, selfV, featV, idxV, WswV, biasV, outV, nrowsV, bid - c_blocks, t);
}

// ---------------- g = sum_r lv[r][:] ----------------
__global__ void zero_g(float* g) { g[threadIdx.x] = 0.f; }

__global__ __launch_bounds__(NT) void reduce_kernel(
    const u16* __restrict__ lv, float* __restrict__ g, int nrows)
{
  __shared__ float sh[NT];
  const int t = threadIdx.x;
  const int d = t & 127, rh = t >> 7;
  float p = 0.f;
  for (int r = blockIdx.x * 2 + rh; r < nrows; r += gridDim.x * 2)
    p += b2f(lv[(size_t)r * DD + d]);
  sh[t] = p;
  __syncthreads();
  if (t < 128) atomicAdd(&g[d], sh[t] + sh[t + 128]);
}

// ------------- Q[r] = b_q + dot(Wq[0:128], g) + dot(Wq[128:256], lv[r]) -------------
__global__ __launch_bounds__(NT) void final_kernel(
    const u16* __restrict__ lv, const float* __restrict__ g,
    const float* __restrict__ Wq, const float* __restrict__ bq,
    float* __restrict__ out)
{
  const int t = threadIdx.x, wave = t >> 6, l = t & 63;
  const float2 wg = *(const float2*)(Wq + 2 * l);
  const float2 wl = *(const float2*)(Wq + DD + 2 * l);
  const float2 gv = *(const float2*)(g + 2 * l);
  float q = wg.x * gv.x + wg.y * gv.y;
#pragma unroll
  for (int off = 32; off; off >>= 1) q += __shfl_down(q, off);
  const float qg = __shfl(q, 0) + bq[0];

  const int r0w = blockIdx.x * 64 + wave * 16;
#pragma unroll
  for (int i = 0; i < 16; ++i) {
    const int r = r0w + i;
    if (r >= NVV) break;
    u32 v = *(const u32*)(lv + (size_t)r * DD + 2 * l);
    float p = wl.x * b2f((u16)(v & 0xFFFF)) + wl.y * b2f((u16)(v >> 16));
#pragma unroll
    for (int off = 32; off; off >>= 1) p += __shfl_down(p, off);
    if (l == 0) out[r] = qg + p;
  }
}

extern "C" void kernel_launch(void* const* d_in, const int* in_sizes, int n_in,
                              void* d_out, int out_size, void* d_ws, size_t ws_size,
                              hipStream_t stream) {
  const float* x    = (const float*)d_in[0];
  const int*   vci  = (const int*)d_in[1];   // var_constr_index [NV][16] -> gathers from lc
  const int*   cvi  = (const int*)d_in[2];   // constr_var_index [NC][16] -> gathers from lv
  const float* W_iv = (const float*)d_in[3];
  const float* b_iv = (const float*)d_in[4];
  const float* W_ic = (const float*)d_in[5];
  const float* b_ic = (const float*)d_in[6];
  const float* W_v  = (const float*)d_in[7];
  const float* b_v  = (const float*)d_in[8];
  const float* W_c  = (const float*)d_in[9];
  const float* b_c  = (const float*)d_in[10];
  const float* W_q  = (const float*)d_in[11];
  const float* b_q  = (const float*)d_in[12];
  float* out = (float*)d_out;

  // workspace: g | xb | Wvsw | Wcsw | Wivsw | Wicsw | lv0 | lc0 | lv1 | lc1
  float* g = (float*)d_ws;
  u16* base = (u16*)((char*)d_ws + 512);
  const size_t nodef = (size_t)NVV * DD;
  u16* xb    = base;                               // 100000*32
  u16* Wvsw  = xb + (size_t)(NVV + NCC) * FIN;
  u16* Wcsw  = Wvsw + (size_t)DD * INDIM;
  u16* Wivsw = Wcsw + (size_t)DD * INDIM;
  u16* Wicsw = Wivsw + (size_t)DD * FIN;
  u16* lv0   = Wicsw + (size_t)DD * FIN;
  u16* lc0   = lv0 + nodef;
  u16* lv1   = lc0 + nodef;
  u16* lc1   = lv1 + nodef;
  u16* xvb   = xb;
  u16* xcb   = xb + (size_t)NVV * FIN;

  dim3 blk(NT);

  swizzle_all<<<40, blk, 0, stream>>>(W_v, W_c, W_iv, W_ic, Wvsw, Wcsw, Wivsw, Wicsw);
  init_fused<<<2 * GRID_HALF, blk, 0, stream>>>(x, Wivsw, Wicsw, b_iv, b_ic,
                                                lv0, lc0, xvb, xcb);

  // iteration 0: lc1 = f(gather lv0, lc0); lv1 = f(gather lc0, lv0)
  layer_merged<<<2 * GRID_HALF, blk, 0, stream>>>(
      lv0, lc0, xcb, cvi, Wcsw, b_c, lc1, NCC,
      lc0, lv0, xvb, vci, Wvsw, b_v, lv1, NVV, GRID_HALF);
  // iteration 1: lc0 = f(gather lv1, lc1); lv0 = f(gather lc1, lv1)
  layer_merged<<<2 * GRID_HALF, blk, 0, stream>>>(
      lv1, lc1, xcb, cvi, Wcsw, b_c, lc0, NCC,
      lc1, lv1, xvb, vci, Wvsw, b_v, lv0, NVV, GRID_HALF);
  // iteration 2: only lv needed (last lc update is dead in the reference)
  layer_merged<<<GRID_HALF, blk, 0, stream>>>(
      lv0, lc0, xcb, cvi, Wcsw, b_c, lc1, NCC,   // unused side
      lc0, lv0, xvb, vci, Wvsw, b_v, lv1, NVV, 0);

  zero_g<<<1, 128, 0, stream>>>(g);
  reduce_kernel<<<256, blk, 0, stream>>>(lv1, g, NVV);
  final_kernel<<<GRID_HALF, blk, 0, stream>>>(lv1, g, W_q, b_q, out);
}

// Round 6
// 365.985 us; speedup vs baseline: 1.4165x; 1.0335x over previous
//
#include <hip/hip_runtime.h>

#define NVV 50000
#define NCC 50000
#define DD 128
#define FIN 32
#define INDIM 288
#define DEG 16

typedef unsigned short u16;
typedef unsigned int u32;
typedef __attribute__((ext_vector_type(8))) short short8;
typedef __attribute__((ext_vector_type(4))) float f32x4;
typedef __attribute__((ext_vector_type(2))) float f32x2;

constexpr int NT = 256;
constexpr int GRID_HALF = 782;   // ceil(50000/64)

__device__ __forceinline__ float b2f(u16 b) {
  union { u32 u; float f; } v; v.u = ((u32)b) << 16; return v.f;
}
__device__ __forceinline__ u16 f2b(float f) {
  union { float f; u32 u; } v; v.f = f;
  u32 u = v.u + 0x7FFFu + ((v.u >> 16) & 1u);
  return (u16)(u >> 16);
}
__device__ __forceinline__ float bits2f(u32 u) {
  union { u32 u; float f; } v; v.u = u; return v.f;
}
__device__ __forceinline__ u32 pack2(float a, float b) {
  return (u32)f2b(a) | ((u32)f2b(b) << 16);
}

// async 16B global->LDS DMA: per-lane global addr, LDS dest = base + lane*16
__device__ __forceinline__ void dma16(const void* g, void* l) {
  __builtin_amdgcn_global_load_lds(
      (__attribute__((address_space(1))) void*)g,
      (__attribute__((address_space(3))) void*)l, 16, 0, 0);
}

// -------- all weights fp32 -> bf16 MFMA B-fragment order, one kernel --------
__global__ __launch_bounds__(NT) void swizzle_all(
    const float* __restrict__ Wv, const float* __restrict__ Wc,
    const float* __restrict__ Wiv, const float* __restrict__ Wic,
    u16* __restrict__ Wvsw, u16* __restrict__ Wcsw,
    u16* __restrict__ Wivsw, u16* __restrict__ Wicsw)
{
  int t = blockIdx.x * NT + threadIdx.x;
  if (t >= 10240) return;
  const float* W; u16* out; int f; int indim;
  if (t < 4608)       { W = Wv;  out = Wvsw;  f = t;        indim = INDIM; }
  else if (t < 9216)  { W = Wc;  out = Wcsw;  f = t - 4608; indim = INDIM; }
  else if (t < 9728)  { W = Wiv; out = Wivsw; f = t - 9216; indim = FIN; }
  else                { W = Wic; out = Wicsw; f = t - 9728; indim = FIN; }
  int lane = f & 63, nt = (f >> 6) & 7, kt = f >> 9;
  int li = lane & 15, quad = lane >> 4;
  const float* src = W + (size_t)(nt * 16 + li) * indim + kt * 32 + quad * 8;
  float4 a = *(const float4*)src, b = *(const float4*)(src + 4);
  u32 o[4] = { pack2(a.x, a.y), pack2(a.z, a.w), pack2(b.x, b.y), pack2(b.z, b.w) };
  *(int4*)(out + (size_t)f * 8) = *(int4*)o;
}

// -------- init (MFMA, fused x->bf16 feat emit): out = bf16(x @ W^T + b) --------
__global__ __launch_bounds__(NT) void init_fused(
    const float* __restrict__ x,
    const u16* __restrict__ Wivsw, const u16* __restrict__ Wicsw,
    const float* __restrict__ b_iv, const float* __restrict__ b_ic,
    u16* __restrict__ lv0, u16* __restrict__ lc0,
    u16* __restrict__ xvb, u16* __restrict__ xcb)
{
  const int bid = blockIdx.x;
  const bool isC = bid >= GRID_HALF;
  const int lb = isC ? bid - GRID_HALF : bid;
  const float* xs = x + (isC ? (size_t)NVV * FIN : 0);
  const u16* Wsw = isC ? Wicsw : Wivsw;
  const float* bias = isC ? b_ic : b_iv;
  u16* out  = isC ? lc0 : lv0;
  u16* feat = isC ? xcb : xvb;
  const int nrows = isC ? NCC : NVV;

  const int t = threadIdx.x;
  const int r0 = lb * 64;

  {
    const int row = r0 + (t >> 2);
    if (row < nrows) {
      const float* src = xs + (size_t)row * FIN + (t & 3) * 8;
      float4 a = *(const float4*)src, b = *(const float4*)(src + 4);
      u32 o[4] = { pack2(a.x, a.y), pack2(a.z, a.w), pack2(b.x, b.y), pack2(b.z, b.w) };
      *(int4*)(feat + (size_t)row * FIN + (t & 3) * 8) = *(int4*)o;
    }
  }

  const int wave = t >> 6, l = t & 63;
  const int quad = l >> 4, li = l & 15;
  const int r0w = r0 + wave * 16;
  int rowm = r0w + li;
  if (rowm >= nrows) rowm = nrows - 1;

  short8 afrag;
  {
    const float* src = xs + (size_t)rowm * FIN + quad * 8;
    float4 a = *(const float4*)src, b = *(const float4*)(src + 4);
    u32 o[4] = { pack2(a.x, a.y), pack2(a.z, a.w), pack2(b.x, b.y), pack2(b.z, b.w) };
    afrag = *(short8*)o;
  }

  f32x4 acc[8];
#pragma unroll
  for (int nt = 0; nt < 8; ++nt) acc[nt] = (f32x4){0.f, 0.f, 0.f, 0.f};
#pragma unroll
  for (int nt = 0; nt < 8; ++nt) {
    short8 b = *(const short8*)(Wsw + (size_t)(nt * 64 + l) * 8);
    acc[nt] = __builtin_amdgcn_mfma_f32_16x16x32_bf16(afrag, b, acc[nt], 0, 0, 0);
  }

  const int rbase = r0w + quad * 4;
#pragma unroll
  for (int nt = 0; nt < 8; ++nt) {
    const int col = nt * 16 + li;
    const float bv = bias[col];
#pragma unroll
    for (int i = 0; i < 4; ++i) {
      const int row = rbase + i;
      if (row < nrows) out[(size_t)row * DD + col] = f2b(acc[nt][i] + bv);
    }
  }
}

// ---- gather ring helpers ----
__device__ __forceinline__ void issue_group(const char* gp, int offj, char* slotbase) {
  const char* rp = gp + (size_t)(u32)offj;
#pragma unroll
  for (int k2 = 0; k2 < 4; ++k2)
    dma16(rp + k2 * 64, slotbase + k2 * 1024);
}
__device__ __forceinline__ void consume_slot(const char* sb, f32x2 (&sagg)[4][4]) {
#pragma unroll
  for (int k2 = 0; k2 < 4; ++k2) {
    int4 v = *(const int4*)(sb + k2 * 1024);
    const u32* w = (const u32*)&v;
#pragma unroll
    for (int p = 0; p < 4; ++p)
      sagg[k2][p] += (f32x2){bits2f(w[p] << 16), bits2f(w[p] & 0xFFFF0000u)};
  }
}

// ------------- fused layer body: out = bf16([gather|self|feat] @ W^T + b) -------------
// Gather via global_load_lds ring: 16 DMA instrs (256 lines) outstanding per wave,
// zero VGPR payload. Wave-private 16KB LDS window, no __syncthreads needed.
__device__ __forceinline__ void layer_body(
    const u16* __restrict__ gsrc, const u16* __restrict__ self,
    const u16* __restrict__ feat, const int* __restrict__ idx,
    const u16* __restrict__ Wsw, const float* __restrict__ bias,
    u16* __restrict__ out, int nrows, int bid, int t, char* smem)
{
  const int wave = t >> 6, l = t & 63;
  const int quad = l >> 4, li = l & 15;
  const int r0w = bid * 64 + wave * 16;

  // lane l holds idx[r0w + (l>>2)][(l&3)*4 .. +3]
  int4 iv;
  {
    int rload = r0w + (l >> 2);
    if (rload >= nrows) rload = nrows - 1;
    iv = *(const int4*)(idx + (size_t)rload * DEG + (l & 3) * 4);
  }
  int off[DEG];
#pragma unroll
  for (int j = 0; j < DEG; ++j) {
    int comp = ((j & 3) == 0) ? iv.x : ((j & 3) == 1) ? iv.y : ((j & 3) == 2) ? iv.z : iv.w;
    off[j] = __shfl(comp, (li << 2) + (j >> 2)) << 8;  // * 256 B per bf16 row
  }

  int rowm = r0w + li;
  if (rowm >= nrows) rowm = nrows - 1;

  f32x4 acc[8];
#pragma unroll
  for (int nt = 0; nt < 8; ++nt) acc[nt] = (f32x4){0.f, 0.f, 0.f, 0.f};

  // ---- dense tiles first: feat (kt=8) + self (kt=4..7); all their VMEM
  // completes before the ring so the vmcnt FIFO stays exclusively ours ----
  {
    short8 a = *(const short8*)(feat + (size_t)rowm * FIN + quad * 8);
#pragma unroll
    for (int nt = 0; nt < 8; ++nt) {
      short8 b = *(const short8*)(Wsw + (size_t)((8 * 8 + nt) * 64 + l) * 8);
      acc[nt] = __builtin_amdgcn_mfma_f32_16x16x32_bf16(a, b, acc[nt], 0, 0, 0);
    }
  }
#pragma unroll
  for (int k2 = 0; k2 < 4; ++k2) {
    short8 a = *(const short8*)(self + (size_t)rowm * DD + k2 * 32 + quad * 8);
#pragma unroll
    for (int nt = 0; nt < 8; ++nt) {
      short8 b = *(const short8*)(Wsw + (size_t)(((4 + k2) * 8 + nt) * 64 + l) * 8);
      acc[nt] = __builtin_amdgcn_mfma_f32_16x16x32_bf16(a, b, acc[nt], 0, 0, 0);
    }
  }

  // ---- gather ring ----
  f32x2 sagg[4][4];
#pragma unroll
  for (int k2 = 0; k2 < 4; ++k2)
#pragma unroll
    for (int p = 0; p < 4; ++p) sagg[k2][p] = (f32x2){0.f, 0.f};

  char* wb = smem + wave * 16384;            // 4 slots x 4KB, wave-private
  const char* gp = (const char*)gsrc + quad * 16;

  asm volatile("s_waitcnt vmcnt(0)" ::: "memory");  // drain: FIFO = ours only

  issue_group(gp, off[0], wb);
  issue_group(gp, off[1], wb + 4096);
  issue_group(gp, off[2], wb + 8192);
  issue_group(gp, off[3], wb + 12288);

#define RING_STEP(J, VN, IJ)                                         \
  asm volatile("s_waitcnt vmcnt(" #VN ")" ::: "memory");             \
  consume_slot(wb + ((J) & 3) * 4096 + l * 16, sagg);                \
  asm volatile("s_waitcnt lgkmcnt(0)" ::: "memory");                 \
  issue_group(gp, off[IJ], wb + ((J) & 3) * 4096);
#define RING_TAIL(J, VN)                                             \
  asm volatile("s_waitcnt vmcnt(" #VN ")" ::: "memory");             \
  consume_slot(wb + ((J) & 3) * 4096 + l * 16, sagg);

  RING_STEP(0, 12, 4)   RING_STEP(1, 12, 5)   RING_STEP(2, 12, 6)
  RING_STEP(3, 12, 7)   RING_STEP(4, 12, 8)   RING_STEP(5, 12, 9)
  RING_STEP(6, 12, 10)  RING_STEP(7, 12, 11)  RING_STEP(8, 12, 12)
  RING_STEP(9, 12, 13)  RING_STEP(10, 12, 14) RING_STEP(11, 12, 15)
  RING_TAIL(12, 12)     RING_TAIL(13, 8)      RING_TAIL(14, 4)
  RING_TAIL(15, 0)
#undef RING_STEP
#undef RING_TAIL

  // ---- gather-tile MFMAs (kt = 0..3) ----
#pragma unroll
  for (int k2 = 0; k2 < 4; ++k2) {
    u32 a_bits[4];
#pragma unroll
    for (int p = 0; p < 4; ++p) a_bits[p] = pack2(sagg[k2][p].x, sagg[k2][p].y);
    short8 a = *(short8*)a_bits;
#pragma unroll
    for (int nt = 0; nt < 8; ++nt) {
      short8 b = *(const short8*)(Wsw + (size_t)((k2 * 8 + nt) * 64 + l) * 8);
      acc[nt] = __builtin_amdgcn_mfma_f32_16x16x32_bf16(a, b, acc[nt], 0, 0, 0);
    }
  }

  const int rbase = r0w + quad * 4;
#pragma unroll
  for (int nt = 0; nt < 8; ++nt) {
    const int col = nt * 16 + li;
    const float bv = bias[col];
#pragma unroll
    for (int i = 0; i < 4; ++i) {
      const int row = rbase + i;
      if (row < nrows) out[(size_t)row * DD + col] = f2b(acc[nt][i] + bv);
    }
  }
}

// merged: blocks [0,c_blocks) do the C update, the rest do the V update.
__global__ __launch_bounds__(NT, 2) void layer_merged(
    const u16* gsrcC, const u16* selfC, const u16* featC, const int* idxC,
    const u16* WswC, const float* biasC, u16* outC, int nrowsC,
    const u16* gsrcV, const u16* selfV, const u16* featV, const int* idxV,
    const u16* WswV, const float* biasV, u16* outV, int nrowsV,
    int c_blocks)
{
  __shared__ char smem[65536];   // 4 waves x 4 slots x 4KB
  const int bid = blockIdx.x;
  const int t = threadIdx.x;
  if (bid < c_blocks)
    layer_body(gsrcC, selfC, featC, idxC, WswC, biasC, outC, nrowsC, bid, t, smem);
  else
    layer_body(gsrcV, selfV, featV, idxV, WswV, biasV, outV, nrowsV, bid - c_blocks, t, smem);
}

// ---------------- g = sum_r lv[r][:] ----------------
__global__ void zero_g(float* g) { g[threadIdx.x] = 0.f; }

__global__ __launch_bounds__(NT) void reduce_kernel(
    const u16* __restrict__ lv, float* __restrict__ g, int nrows)
{
  __shared__ float sh[NT];
  const int t = threadIdx.x;
  const int d = t & 127, rh = t >> 7;
  float p = 0.f;
  for (int r = blockIdx.x * 2 + rh; r < nrows; r += gridDim.x * 2)
    p += b2f(lv[(size_t)r * DD + d]);
  sh[t] = p;
  __syncthreads();
  if (t < 128) atomicAdd(&g[d], sh[t] + sh[t + 128]);
}

// ------------- Q[r] = b_q + dot(Wq[0:128], g) + dot(Wq[128:256], lv[r]) -------------
__global__ __launch_bounds__(NT) void final_kernel(
    const u16* __restrict__ lv, const float* __restrict__ g,
    const float* __restrict__ Wq, const float* __restrict__ bq,
    float* __restrict__ out)
{
  const int t = threadIdx.x, wave = t >> 6, l = t & 63;
  const float2 wg = *(const float2*)(Wq + 2 * l);
  const float2 wl = *(const float2*)(Wq + DD + 2 * l);
  const float2 gv = *(const float2*)(g + 2 * l);
  float q = wg.x * gv.x + wg.y * gv.y;
#pragma unroll
  for (int off = 32; off; off >>= 1) q += __shfl_down(q, off);
  const float qg = __shfl(q, 0) + bq[0];

  const int r0w = blockIdx.x * 64 + wave * 16;
#pragma unroll
  for (int i = 0; i < 16; ++i) {
    const int r = r0w + i;
    if (r >= NVV) break;
    u32 v = *(const u32*)(lv + (size_t)r * DD + 2 * l);
    float p = wl.x * b2f((u16)(v & 0xFFFF)) + wl.y * b2f((u16)(v >> 16));
#pragma unroll
    for (int off = 32; off; off >>= 1) p += __shfl_down(p, off);
    if (l == 0) out[r] = qg + p;
  }
}

extern "C" void kernel_launch(void* const* d_in, const int* in_sizes, int n_in,
                              void* d_out, int out_size, void* d_ws, size_t ws_size,
                              hipStream_t stream) {
  const float* x    = (const float*)d_in[0];
  const int*   vci  = (const int*)d_in[1];   // var_constr_index [NV][16] -> gathers from lc
  const int*   cvi  = (const int*)d_in[2];   // constr_var_index [NC][16] -> gathers from lv
  const float* W_iv = (const float*)d_in[3];
  const float* b_iv = (const float*)d_in[4];
  const float* W_ic = (const float*)d_in[5];
  const float* b_ic = (const float*)d_in[6];
  const float* W_v  = (const float*)d_in[7];
  const float* b_v  = (const float*)d_in[8];
  const float* W_c  = (const float*)d_in[9];
  const float* b_c  = (const float*)d_in[10];
  const float* W_q  = (const float*)d_in[11];
  const float* b_q  = (const float*)d_in[12];
  float* out = (float*)d_out;

  // workspace: g | xb | Wvsw | Wcsw | Wivsw | Wicsw | lv0 | lc0 | lv1 | lc1
  float* g = (float*)d_ws;
  u16* base = (u16*)((char*)d_ws + 512);
  const size_t nodef = (size_t)NVV * DD;
  u16* xb    = base;
  u16* Wvsw  = xb + (size_t)(NVV + NCC) * FIN;
  u16* Wcsw  = Wvsw + (size_t)DD * INDIM;
  u16* Wivsw = Wcsw + (size_t)DD * INDIM;
  u16* Wicsw = Wivsw + (size_t)DD * FIN;
  u16* lv0   = Wicsw + (size_t)DD * FIN;
  u16* lc0   = lv0 + nodef;
  u16* lv1   = lc0 + nodef;
  u16* lc1   = lv1 + nodef;
  u16* xvb   = xb;
  u16* xcb   = xb + (size_t)NVV * FIN;

  dim3 blk(NT);

  swizzle_all<<<40, blk, 0, stream>>>(W_v, W_c, W_iv, W_ic, Wvsw, Wcsw, Wivsw, Wicsw);
  init_fused<<<2 * GRID_HALF, blk, 0, stream>>>(x, Wivsw, Wicsw, b_iv, b_ic,
                                                lv0, lc0, xvb, xcb);

  // iteration 0: lc1 = f(gather lv0, lc0); lv1 = f(gather lc0, lv0)
  layer_merged<<<2 * GRID_HALF, blk, 0, stream>>>(
      lv0, lc0, xcb, cvi, Wcsw, b_c, lc1, NCC,
      lc0, lv0, xvb, vci, Wvsw, b_v, lv1, NVV, GRID_HALF);
  // iteration 1: lc0 = f(gather lv1, lc1); lv0 = f(gather lc1, lv1)
  layer_merged<<<2 * GRID_HALF, blk, 0, stream>>>(
      lv1, lc1, xcb, cvi, Wcsw, b_c, lc0, NCC,
      lc1, lv1, xvb, vci, Wvsw, b_v, lv0, NVV, GRID_HALF);
  // iteration 2: only lv needed (last lc update is dead in the reference)
  layer_merged<<<GRID_HALF, blk, 0, stream>>>(
      lv0, lc0, xcb, cvi, Wcsw, b_c, lc1, NCC,   // unused side
      lc0, lv0, xvb, vci, Wvsw, b_v, lv1, NVV, 0);

  zero_g<<<1, 128, 0, stream>>>(g);
  reduce_kernel<<<256, blk, 0, stream>>>(lv1, g, NVV);
  final_kernel<<<GRID_HALF, blk, 0, stream>>>(lv1, g, W_q, b_q, out);
}

// Round 7
// 347.732 us; speedup vs baseline: 1.4909x; 1.0525x over previous
//
#include <hip/hip_runtime.h>

#define NVV 50000
#define NCC 50000
#define DD 128
#define FIN 32
#define INDIM 288
#define DEG 16

typedef unsigned short u16;
typedef unsigned char u8;
typedef unsigned int u32;
typedef __attribute__((ext_vector_type(8))) short short8;
typedef __attribute__((ext_vector_type(4))) float f32x4;
typedef __attribute__((ext_vector_type(2))) float f32x2;

constexpr int NT = 256;
constexpr int GRID_HALF = 782;   // ceil(50000/64)

__device__ __forceinline__ float b2f(u16 b) {
  union { u32 u; float f; } v; v.u = ((u32)b) << 16; return v.f;
}
__device__ __forceinline__ u16 f2b(float f) {
  union { float f; u32 u; } v; v.f = f;
  u32 u = v.u + 0x7FFFu + ((v.u >> 16) & 1u);
  return (u16)(u >> 16);
}
__device__ __forceinline__ float bits2f(u32 u) {
  union { u32 u; float f; } v; v.u = u; return v.f;
}
__device__ __forceinline__ u32 pack2(float a, float b) {
  return (u32)f2b(a) | ((u32)f2b(b) << 16);
}
__device__ __forceinline__ u8 f2fp8(float f) {
  return (u8)(__builtin_amdgcn_cvt_pk_fp8_f32(f, f, 0, false) & 0xFF);
}

// async 16B global->LDS DMA: per-lane global addr, LDS dest = base + lane*16
__device__ __forceinline__ void dma16(const void* g, void* l) {
  __builtin_amdgcn_global_load_lds(
      (__attribute__((address_space(1))) void*)g,
      (__attribute__((address_space(3))) void*)l, 16, 0, 0);
}

// -------- all weights fp32 -> bf16 MFMA B-fragment order, one kernel --------
__global__ __launch_bounds__(NT) void swizzle_all(
    const float* __restrict__ Wv, const float* __restrict__ Wc,
    const float* __restrict__ Wiv, const float* __restrict__ Wic,
    u16* __restrict__ Wvsw, u16* __restrict__ Wcsw,
    u16* __restrict__ Wivsw, u16* __restrict__ Wicsw)
{
  int t = blockIdx.x * NT + threadIdx.x;
  if (t >= 10240) return;
  const float* W; u16* out; int f; int indim;
  if (t < 4608)       { W = Wv;  out = Wvsw;  f = t;        indim = INDIM; }
  else if (t < 9216)  { W = Wc;  out = Wcsw;  f = t - 4608; indim = INDIM; }
  else if (t < 9728)  { W = Wiv; out = Wivsw; f = t - 9216; indim = FIN; }
  else                { W = Wic; out = Wicsw; f = t - 9728; indim = FIN; }
  int lane = f & 63, nt = (f >> 6) & 7, kt = f >> 9;
  int li = lane & 15, quad = lane >> 4;
  const float* src = W + (size_t)(nt * 16 + li) * indim + kt * 32 + quad * 8;
  float4 a = *(const float4*)src, b = *(const float4*)(src + 4);
  u32 o[4] = { pack2(a.x, a.y), pack2(a.z, a.w), pack2(b.x, b.y), pack2(b.z, b.w) };
  *(int4*)(out + (size_t)f * 8) = *(int4*)o;
}

// -------- init (MFMA, fused x->bf16 feat emit): out = bf16(x @ W^T + b) + fp8 copy --------
__global__ __launch_bounds__(NT) void init_fused(
    const float* __restrict__ x,
    const u16* __restrict__ Wivsw, const u16* __restrict__ Wicsw,
    const float* __restrict__ b_iv, const float* __restrict__ b_ic,
    u16* __restrict__ lv0, u16* __restrict__ lc0,
    u8* __restrict__ lv08, u8* __restrict__ lc08,
    u16* __restrict__ xvb, u16* __restrict__ xcb)
{
  const int bid = blockIdx.x;
  const bool isC = bid >= GRID_HALF;
  const int lb = isC ? bid - GRID_HALF : bid;
  const float* xs = x + (isC ? (size_t)NVV * FIN : 0);
  const u16* Wsw = isC ? Wicsw : Wivsw;
  const float* bias = isC ? b_ic : b_iv;
  u16* out  = isC ? lc0 : lv0;
  u8*  out8 = isC ? lc08 : lv08;
  u16* feat = isC ? xcb : xvb;
  const int nrows = isC ? NCC : NVV;

  const int t = threadIdx.x;
  const int r0 = lb * 64;

  {
    const int row = r0 + (t >> 2);
    if (row < nrows) {
      const float* src = xs + (size_t)row * FIN + (t & 3) * 8;
      float4 a = *(const float4*)src, b = *(const float4*)(src + 4);
      u32 o[4] = { pack2(a.x, a.y), pack2(a.z, a.w), pack2(b.x, b.y), pack2(b.z, b.w) };
      *(int4*)(feat + (size_t)row * FIN + (t & 3) * 8) = *(int4*)o;
    }
  }

  const int wave = t >> 6, l = t & 63;
  const int quad = l >> 4, li = l & 15;
  const int r0w = r0 + wave * 16;
  int rowm = r0w + li;
  if (rowm >= nrows) rowm = nrows - 1;

  short8 afrag;
  {
    const float* src = xs + (size_t)rowm * FIN + quad * 8;
    float4 a = *(const float4*)src, b = *(const float4*)(src + 4);
    u32 o[4] = { pack2(a.x, a.y), pack2(a.z, a.w), pack2(b.x, b.y), pack2(b.z, b.w) };
    afrag = *(short8*)o;
  }

  f32x4 acc[8];
#pragma unroll
  for (int nt = 0; nt < 8; ++nt) acc[nt] = (f32x4){0.f, 0.f, 0.f, 0.f};
#pragma unroll
  for (int nt = 0; nt < 8; ++nt) {
    short8 b = *(const short8*)(Wsw + (size_t)(nt * 64 + l) * 8);
    acc[nt] = __builtin_amdgcn_mfma_f32_16x16x32_bf16(afrag, b, acc[nt], 0, 0, 0);
  }

  const int rbase = r0w + quad * 4;
#pragma unroll
  for (int nt = 0; nt < 8; ++nt) {
    const int col = nt * 16 + li;
    const float bv = bias[col];
#pragma unroll
    for (int i = 0; i < 4; ++i) {
      const int row = rbase + i;
      if (row < nrows) {
        float v = acc[nt][i] + bv;
        out[(size_t)row * DD + col] = f2b(v);
        out8[(size_t)row * DD + col] = f2fp8(v);
      }
    }
  }
}

// ---- gather ring helpers ----
// bf16: row = 256B = 4 lines; 4 dma16 per neighbor; slot 4KB
__device__ __forceinline__ void issue_group16(const char* gp, int offj, char* slotbase) {
  const char* rp = gp + (size_t)(u32)offj;
#pragma unroll
  for (int k2 = 0; k2 < 4; ++k2)
    dma16(rp + k2 * 64, slotbase + k2 * 1024);
}
__device__ __forceinline__ void consume_slot16(const char* sb, float (&sagg)[4][8]) {
#pragma unroll
  for (int k2 = 0; k2 < 4; ++k2) {
    int4 v = *(const int4*)(sb + k2 * 1024);
    const u32* w = (const u32*)&v;
#pragma unroll
    for (int p = 0; p < 4; ++p) {
      sagg[k2][2 * p]     += bits2f(w[p] << 16);
      sagg[k2][2 * p + 1] += bits2f(w[p] & 0xFFFF0000u);
    }
  }
}
// fp8: row = 128B = 2 lines; 2 dma16 per neighbor; slot 2KB
// layout: chunk c (16B) of dest-row li at slot + c*256 + li*16
__device__ __forceinline__ void issue_group8(const char* gp, int offj, char* slotbase) {
  const char* rp = gp + (size_t)(u32)offj;
  dma16(rp, slotbase);
  dma16(rp + 64, slotbase + 1024);
}
__device__ __forceinline__ void consume_slot8(const char* slot, int li, int quad,
                                              float (&sagg)[4][8]) {
  const int half = quad & 1, c2 = quad >> 1;
#pragma unroll
  for (int kt = 0; kt < 4; ++kt) {
    int4 v = *(const int4*)(slot + (2 * kt + c2) * 256 + li * 16);
    u32 w0 = half ? (u32)v.z : (u32)v.x;
    u32 w1 = half ? (u32)v.w : (u32)v.y;
    f32x2 a0 = __builtin_amdgcn_cvt_pk_f32_fp8(w0, false);
    f32x2 a1 = __builtin_amdgcn_cvt_pk_f32_fp8(w0, true);
    f32x2 a2 = __builtin_amdgcn_cvt_pk_f32_fp8(w1, false);
    f32x2 a3 = __builtin_amdgcn_cvt_pk_f32_fp8(w1, true);
    sagg[kt][0] += a0.x; sagg[kt][1] += a0.y;
    sagg[kt][2] += a1.x; sagg[kt][3] += a1.y;
    sagg[kt][4] += a2.x; sagg[kt][5] += a2.y;
    sagg[kt][6] += a3.x; sagg[kt][7] += a3.y;
  }
}

// ------------- fused layer body -------------
template <bool F8, bool W8, bool GACC>
__device__ __forceinline__ void layer_body(
    const void* __restrict__ gsrc, const u16* __restrict__ self,
    const u16* __restrict__ feat, const int* __restrict__ idx,
    const u16* __restrict__ Wsw, const float* __restrict__ bias,
    u16* __restrict__ out, u8* __restrict__ out8, float* __restrict__ g,
    int nrows, int bid, int t, char* smem)
{
  const int wave = t >> 6, l = t & 63;
  const int quad = l >> 4, li = l & 15;
  const int r0w = bid * 64 + wave * 16;

  int4 iv;
  {
    int rload = r0w + (l >> 2);
    if (rload >= nrows) rload = nrows - 1;
    iv = *(const int4*)(idx + (size_t)rload * DEG + (l & 3) * 4);
  }
  int off[DEG];
#pragma unroll
  for (int j = 0; j < DEG; ++j) {
    int comp = ((j & 3) == 0) ? iv.x : ((j & 3) == 1) ? iv.y : ((j & 3) == 2) ? iv.z : iv.w;
    off[j] = __shfl(comp, (li << 2) + (j >> 2)) << (F8 ? 7 : 8);
  }

  int rowm = r0w + li;
  if (rowm >= nrows) rowm = nrows - 1;

  f32x4 acc[8];
#pragma unroll
  for (int nt = 0; nt < 8; ++nt) acc[nt] = (f32x4){0.f, 0.f, 0.f, 0.f};

  // ---- dense tiles first (their VMEM drains before the ring) ----
  {
    short8 a = *(const short8*)(feat + (size_t)rowm * FIN + quad * 8);
#pragma unroll
    for (int nt = 0; nt < 8; ++nt) {
      short8 b = *(const short8*)(Wsw + (size_t)((8 * 8 + nt) * 64 + l) * 8);
      acc[nt] = __builtin_amdgcn_mfma_f32_16x16x32_bf16(a, b, acc[nt], 0, 0, 0);
    }
  }
#pragma unroll
  for (int k2 = 0; k2 < 4; ++k2) {
    short8 a = *(const short8*)(self + (size_t)rowm * DD + k2 * 32 + quad * 8);
#pragma unroll
    for (int nt = 0; nt < 8; ++nt) {
      short8 b = *(const short8*)(Wsw + (size_t)(((4 + k2) * 8 + nt) * 64 + l) * 8);
      acc[nt] = __builtin_amdgcn_mfma_f32_16x16x32_bf16(a, b, acc[nt], 0, 0, 0);
    }
  }

  // ---- gather ring ----
  float sagg[4][8];
#pragma unroll
  for (int k2 = 0; k2 < 4; ++k2)
#pragma unroll
    for (int p = 0; p < 8; ++p) sagg[k2][p] = 0.f;

  asm volatile("s_waitcnt vmcnt(0)" ::: "memory");  // FIFO = ours only

  if constexpr (F8) {
    char* wb = smem + wave * 8192;               // 4 slots x 2KB
    const char* gp = (const char*)gsrc + quad * 16;
    issue_group8(gp, off[0], wb);
    issue_group8(gp, off[1], wb + 2048);
    issue_group8(gp, off[2], wb + 4096);
    issue_group8(gp, off[3], wb + 6144);
#define R8_STEP(J, IJ)                                               \
    asm volatile("s_waitcnt vmcnt(6)" ::: "memory");                 \
    consume_slot8(wb + ((J) & 3) * 2048, li, quad, sagg);            \
    asm volatile("s_waitcnt lgkmcnt(0)" ::: "memory");               \
    issue_group8(gp, off[IJ], wb + ((J) & 3) * 2048);
#define R8_TAIL(J, VN)                                               \
    asm volatile("s_waitcnt vmcnt(" #VN ")" ::: "memory");           \
    consume_slot8(wb + ((J) & 3) * 2048, li, quad, sagg);
    R8_STEP(0, 4)  R8_STEP(1, 5)  R8_STEP(2, 6)  R8_STEP(3, 7)
    R8_STEP(4, 8)  R8_STEP(5, 9)  R8_STEP(6, 10) R8_STEP(7, 11)
    R8_STEP(8, 12) R8_STEP(9, 13) R8_STEP(10, 14) R8_STEP(11, 15)
    R8_TAIL(12, 6) R8_TAIL(13, 4) R8_TAIL(14, 2)  R8_TAIL(15, 0)
#undef R8_STEP
#undef R8_TAIL
  } else {
    char* wb = smem + wave * 16384;              // 4 slots x 4KB
    const char* gp = (const char*)gsrc + quad * 16;
    issue_group16(gp, off[0], wb);
    issue_group16(gp, off[1], wb + 4096);
    issue_group16(gp, off[2], wb + 8192);
    issue_group16(gp, off[3], wb + 12288);
#define R16_STEP(J, IJ)                                              \
    asm volatile("s_waitcnt vmcnt(12)" ::: "memory");                \
    consume_slot16(wb + ((J) & 3) * 4096 + l * 16, sagg);            \
    asm volatile("s_waitcnt lgkmcnt(0)" ::: "memory");               \
    issue_group16(gp, off[IJ], wb + ((J) & 3) * 4096);
#define R16_TAIL(J, VN)                                              \
    asm volatile("s_waitcnt vmcnt(" #VN ")" ::: "memory");           \
    consume_slot16(wb + ((J) & 3) * 4096 + l * 16, sagg);
    R16_STEP(0, 4)  R16_STEP(1, 5)  R16_STEP(2, 6)  R16_STEP(3, 7)
    R16_STEP(4, 8)  R16_STEP(5, 9)  R16_STEP(6, 10) R16_STEP(7, 11)
    R16_STEP(8, 12) R16_STEP(9, 13) R16_STEP(10, 14) R16_STEP(11, 15)
    R16_TAIL(12, 12) R16_TAIL(13, 8) R16_TAIL(14, 4) R16_TAIL(15, 0)
#undef R16_STEP
#undef R16_TAIL
  }

  // ---- gather-tile MFMAs (kt = 0..3) ----
#pragma unroll
  for (int k2 = 0; k2 < 4; ++k2) {
    u32 a_bits[4];
#pragma unroll
    for (int p = 0; p < 4; ++p) a_bits[p] = pack2(sagg[k2][2 * p], sagg[k2][2 * p + 1]);
    short8 a = *(short8*)a_bits;
#pragma unroll
    for (int nt = 0; nt < 8; ++nt) {
      short8 b = *(const short8*)(Wsw + (size_t)((k2 * 8 + nt) * 64 + l) * 8);
      acc[nt] = __builtin_amdgcn_mfma_f32_16x16x32_bf16(a, b, acc[nt], 0, 0, 0);
    }
  }

  // ---- epilogue ----
  const int rbase = r0w + quad * 4;
  float colsum[8];
#pragma unroll
  for (int nt = 0; nt < 8; ++nt) {
    const int col = nt * 16 + li;
    const float bv = bias[col];
    colsum[nt] = 0.f;
#pragma unroll
    for (int i = 0; i < 4; ++i) {
      const int row = rbase + i;
      if (row < nrows) {
        float v = acc[nt][i] + bv;
        out[(size_t)row * DD + col] = f2b(v);
        if constexpr (W8) out8[(size_t)row * DD + col] = f2fp8(v);
        if constexpr (GACC) colsum[nt] += v;
      }
    }
  }

  if constexpr (GACC) {
    // cross-quad butterfly -> full 64-row col sums on all lanes
#pragma unroll
    for (int nt = 0; nt < 8; ++nt) {
      colsum[nt] += __shfl_xor(colsum[nt], 16);
      colsum[nt] += __shfl_xor(colsum[nt], 32);
    }
    __syncthreads();               // ring LDS dead everywhere; reuse
    float* gsum = (float*)smem;    // [4][128]
    if (quad == 0) {
#pragma unroll
      for (int nt = 0; nt < 8; ++nt) gsum[wave * 128 + nt * 16 + li] = colsum[nt];
    }
    __syncthreads();
    if (t < 128) {
      float tot = gsum[t] + gsum[128 + t] + gsum[256 + t] + gsum[384 + t];
      atomicAdd(&g[t], tot);
    }
  }
}

template <bool F8, bool W8, bool GACC>
__global__ __launch_bounds__(NT, 2) void layer_merged(
    const void* gsrcC, const u16* selfC, const u16* featC, const int* idxC,
    const u16* WswC, const float* biasC, u16* outC, u8* out8C, int nrowsC,
    const void* gsrcV, const u16* selfV, const u16* featV, const int* idxV,
    const u16* WswV, const float* biasV, u16* outV, u8* out8V, int nrowsV,
    float* g, int c_blocks)
{
  __shared__ char smem[F8 ? 32768 : 65536];
  const int bid = blockIdx.x;
  const int t = threadIdx.x;
  if (bid < c_blocks)
    layer_body<F8, W8, GACC>(gsrcC, selfC, featC, idxC, WswC, biasC, outC, out8C,
                             g, nrowsC, bid, t, smem);
  else
    layer_body<F8, W8, GACC>(gsrcV, selfV, featV, idxV, WswV, biasV, outV, out8V,
                             g, nrowsV, bid - c_blocks, t, smem);
}

__global__ void zero_g(float* g) { g[threadIdx.x] = 0.f; }

// ------------- Q[r] = b_q + dot(Wq[0:128], g) + dot(Wq[128:256], lv[r]) -------------
__global__ __launch_bounds__(NT) void final_kernel(
    const u16* __restrict__ lv, const float* __restrict__ g,
    const float* __restrict__ Wq, const float* __restrict__ bq,
    float* __restrict__ out)
{
  const int t = threadIdx.x, wave = t >> 6, l = t & 63;
  const float2 wg = *(const float2*)(Wq + 2 * l);
  const float2 wl = *(const float2*)(Wq + DD + 2 * l);
  const float2 gv = *(const float2*)(g + 2 * l);
  float q = wg.x * gv.x + wg.y * gv.y;
#pragma unroll
  for (int off = 32; off; off >>= 1) q += __shfl_down(q, off);
  const float qg = __shfl(q, 0) + bq[0];

  const int r0w = blockIdx.x * 64 + wave * 16;
#pragma unroll
  for (int i = 0; i < 16; ++i) {
    const int r = r0w + i;
    if (r >= NVV) break;
    u32 v = *(const u32*)(lv + (size_t)r * DD + 2 * l);
    float p = wl.x * b2f((u16)(v & 0xFFFF)) + wl.y * b2f((u16)(v >> 16));
#pragma unroll
    for (int off = 32; off; off >>= 1) p += __shfl_down(p, off);
    if (l == 0) out[r] = qg + p;
  }
}

extern "C" void kernel_launch(void* const* d_in, const int* in_sizes, int n_in,
                              void* d_out, int out_size, void* d_ws, size_t ws_size,
                              hipStream_t stream) {
  const float* x    = (const float*)d_in[0];
  const int*   vci  = (const int*)d_in[1];   // var_constr_index -> gathers from lc
  const int*   cvi  = (const int*)d_in[2];   // constr_var_index -> gathers from lv
  const float* W_iv = (const float*)d_in[3];
  const float* b_iv = (const float*)d_in[4];
  const float* W_ic = (const float*)d_in[5];
  const float* b_ic = (const float*)d_in[6];
  const float* W_v  = (const float*)d_in[7];
  const float* b_v  = (const float*)d_in[8];
  const float* W_c  = (const float*)d_in[9];
  const float* b_c  = (const float*)d_in[10];
  const float* W_q  = (const float*)d_in[11];
  const float* b_q  = (const float*)d_in[12];
  float* out = (float*)d_out;

  float* g = (float*)d_ws;
  u16* base = (u16*)((char*)d_ws + 512);
  const size_t nodef = (size_t)NVV * DD;
  u16* xb    = base;
  u16* Wvsw  = xb + (size_t)(NVV + NCC) * FIN;
  u16* Wcsw  = Wvsw + (size_t)DD * INDIM;
  u16* Wivsw = Wcsw + (size_t)DD * INDIM;
  u16* Wicsw = Wivsw + (size_t)DD * FIN;
  u16* lv0   = Wicsw + (size_t)DD * FIN;
  u16* lc0   = lv0 + nodef;
  u16* lv1   = lc0 + nodef;
  u16* lc1   = lv1 + nodef;
  u8*  lv08  = (u8*)(lc1 + nodef);
  u8*  lc08  = lv08 + nodef;
  u8*  lv18  = lc08 + nodef;
  u8*  lc18  = lv18 + nodef;
  u16* xvb   = xb;
  u16* xcb   = xb + (size_t)NVV * FIN;

  dim3 blk(NT);

  swizzle_all<<<40, blk, 0, stream>>>(W_v, W_c, W_iv, W_ic, Wvsw, Wcsw, Wivsw, Wicsw);
  init_fused<<<2 * GRID_HALF, blk, 0, stream>>>(x, Wivsw, Wicsw, b_iv, b_ic,
                                                lv0, lc0, lv08, lc08, xvb, xcb);
  zero_g<<<1, 128, 0, stream>>>(g);

  // it0: gather fp8 G0 -> write G1 (bf16 + fp8)
  layer_merged<true, true, false><<<2 * GRID_HALF, blk, 0, stream>>>(
      lv08, lc0, xcb, cvi, Wcsw, b_c, lc1, lc18, NCC,
      lc08, lv0, xvb, vci, Wvsw, b_v, lv1, lv18, NVV, g, GRID_HALF);
  // it1: gather fp8 G1 -> write G2 (bf16 only) into lv0/lc0 buffers
  layer_merged<true, false, false><<<2 * GRID_HALF, blk, 0, stream>>>(
      lv18, lc1, xcb, cvi, Wcsw, b_c, lc0, nullptr, NCC,
      lc18, lv1, xvb, vci, Wvsw, b_v, lv0, nullptr, NVV, g, GRID_HALF);
  // it2: V update only, bf16 gather of lc (G2), + fused g accumulation
  layer_merged<false, false, true><<<GRID_HALF, blk, 0, stream>>>(
      lv0, lc0, xcb, cvi, Wcsw, b_c, lc1, nullptr, NCC,   // unused side
      lc0, lv0, xvb, vci, Wvsw, b_v, lv1, nullptr, NVV, g, 0);

  final_kernel<<<GRID_HALF, blk, 0, stream>>>(lv1, g, W_q, b_q, out);
}